// Round 7
// baseline (241.881 us; speedup 1.0000x reference)
//
#include <hip/hip_runtime.h>
#include <math.h>

#define B_   8
#define C_   64
#define CK_  8
#define L_   4096
#define NSPL 2
#define LSPL (L_ / NSPL)
#define S_   72     // P LDS row stride (bf16 elems): 144B, 16B-aligned, ~2-way banks

typedef __attribute__((ext_vector_type(8))) __bf16 bf16x8;
typedef __attribute__((ext_vector_type(4))) __bf16 bf16x4;
typedef __attribute__((ext_vector_type(4))) float  f32x4;

// ---------------- Kernel 1: QKV projection -> bf16 ----------------
// x: [B,C,L] fp32 -> q: [B,L,8] ; kT: [B,L,8] ; vo: [B,C,L]
__global__ __launch_bounds__(256) void qkv_kernel(
    const float* __restrict__ x,
    const float* __restrict__ Wq, const float* __restrict__ bq,
    const float* __restrict__ Wk, const float* __restrict__ bk,
    const float* __restrict__ Wv, const float* __restrict__ bv,
    __bf16* __restrict__ qo, __bf16* __restrict__ ko, __bf16* __restrict__ vo)
{
    __shared__ float LWq[CK_ * C_];
    __shared__ float LWk[CK_ * C_];
    __shared__ float LWv[C_ * C_];      // row-major [c_out][c_in]
    __shared__ __bf16 Lqs[64 * 8];
    __shared__ __bf16 Lks[64 * 8];

    const int tid = threadIdx.x;
    if (tid < 128) {
        ((float4*)LWq)[tid] = ((const float4*)Wq)[tid];
        ((float4*)LWk)[tid] = ((const float4*)Wk)[tid];
    }
    #pragma unroll
    for (int j = 0; j < 4; ++j)
        ((float4*)LWv)[tid + j * 256] = ((const float4*)Wv)[tid + j * 256];
    __syncthreads();

    const int b  = blockIdx.x >> 6;
    const int l0 = (blockIdx.x & 63) << 6;
    const int lg = tid & 15;
    const int g  = tid >> 4;

    float va[4][4];
    float qk[4];
    #pragma unroll
    for (int j = 0; j < 4; ++j) {
        float bb = bv[4 * g + j];
        va[j][0] = bb; va[j][1] = bb; va[j][2] = bb; va[j][3] = bb;
    }
    {
        float bb = (g < 8) ? bq[g] : bk[g - 8];
        qk[0] = bb; qk[1] = bb; qk[2] = bb; qk[3] = bb;
    }
    const float* wqk = (g < 8) ? (LWq + g * C_) : (LWk + (g - 8) * C_);

    const float* xp = x + ((size_t)b * C_) * L_ + l0 + lg * 4;
    #pragma unroll 4
    for (int c4 = 0; c4 < 16; ++c4) {
        float4 xv[4];
        #pragma unroll
        for (int u = 0; u < 4; ++u)
            xv[u] = *(const float4*)(xp + (size_t)(4 * c4 + u) * L_);
        #pragma unroll
        for (int j = 0; j < 4; ++j) {
            float4 wv = ((const float4*)(LWv + (4 * g + j) * C_))[c4];
            float* a = va[j];
            a[0]=fmaf(wv.x,xv[0].x,a[0]); a[1]=fmaf(wv.x,xv[0].y,a[1]); a[2]=fmaf(wv.x,xv[0].z,a[2]); a[3]=fmaf(wv.x,xv[0].w,a[3]);
            a[0]=fmaf(wv.y,xv[1].x,a[0]); a[1]=fmaf(wv.y,xv[1].y,a[1]); a[2]=fmaf(wv.y,xv[1].z,a[2]); a[3]=fmaf(wv.y,xv[1].w,a[3]);
            a[0]=fmaf(wv.z,xv[2].x,a[0]); a[1]=fmaf(wv.z,xv[2].y,a[1]); a[2]=fmaf(wv.z,xv[2].z,a[2]); a[3]=fmaf(wv.z,xv[2].w,a[3]);
            a[0]=fmaf(wv.w,xv[3].x,a[0]); a[1]=fmaf(wv.w,xv[3].y,a[1]); a[2]=fmaf(wv.w,xv[3].z,a[2]); a[3]=fmaf(wv.w,xv[3].w,a[3]);
        }
        {
            float4 wv = ((const float4*)wqk)[c4];
            qk[0]=fmaf(wv.x,xv[0].x,qk[0]); qk[1]=fmaf(wv.x,xv[0].y,qk[1]); qk[2]=fmaf(wv.x,xv[0].z,qk[2]); qk[3]=fmaf(wv.x,xv[0].w,qk[3]);
            qk[0]=fmaf(wv.y,xv[1].x,qk[0]); qk[1]=fmaf(wv.y,xv[1].y,qk[1]); qk[2]=fmaf(wv.y,xv[1].z,qk[2]); qk[3]=fmaf(wv.y,xv[1].w,qk[3]);
            qk[0]=fmaf(wv.z,xv[2].x,qk[0]); qk[1]=fmaf(wv.z,xv[2].y,qk[1]); qk[2]=fmaf(wv.z,xv[2].z,qk[2]); qk[3]=fmaf(wv.z,xv[2].w,qk[3]);
            qk[0]=fmaf(wv.w,xv[3].x,qk[0]); qk[1]=fmaf(wv.w,xv[3].y,qk[1]); qk[2]=fmaf(wv.w,xv[3].z,qk[2]); qk[3]=fmaf(wv.w,xv[3].w,qk[3]);
        }
    }

    #pragma unroll
    for (int j = 0; j < 4; ++j) {
        bf16x4 vv;
        vv[0]=(__bf16)va[j][0]; vv[1]=(__bf16)va[j][1]; vv[2]=(__bf16)va[j][2]; vv[3]=(__bf16)va[j][3];
        *(bf16x4*)(vo + ((size_t)b * C_ + 4 * g + j) * L_ + l0 + lg * 4) = vv;
    }
    #pragma unroll
    for (int u = 0; u < 4; ++u) {
        if (g < 8) Lqs[(lg * 4 + u) * 8 + g]       = (__bf16)qk[u];
        else       Lks[(lg * 4 + u) * 8 + (g - 8)] = (__bf16)qk[u];
    }
    __syncthreads();
    if (tid < 64) {
        *(bf16x8*)(qo + ((size_t)b * L_ + l0 + tid) * 8) = *(bf16x8*)(Lqs + tid * 8);
        *(bf16x8*)(ko + ((size_t)b * L_ + l0 + tid) * 8) = *(bf16x8*)(Lks + tid * 8);
    }
}

// ---------------- Kernel 2: attention phase-1, no K-loop barriers ---------
// Each wave owns its own 64 l-rows per iteration + private LDS P region;
// producer==consumer wave => no __syncthreads inside the loop. Epilogue does
// the cross-wave accumulator reduction (this was the R4-R6 race).
// grid: B * 64(mb) * NSPL. Writes unnormalized partial acc (bf16) + colsums.
__global__ __launch_bounds__(256, 4) void attn_kernel(
    const __bf16* __restrict__ q, const __bf16* __restrict__ kT,
    const __bf16* __restrict__ V,
    __bf16* __restrict__ pacc, float* __restrict__ pcs)
{
    __shared__ __bf16 Pall[4][64 * S_];   // 4 wave-private P tiles [m][l]
    __shared__ float  cs[4][64];

    const int tid  = threadIdx.x;
    const int w    = tid >> 6;
    const int lane = tid & 63;
    const int quad = lane >> 4;
    const int l16  = lane & 15;
    const int lq   = blockIdx.x & (NSPL - 1);
    const int mb   = (blockIdx.x / NSPL) & 63;
    const int b    = blockIdx.x / (NSPL * 64);
    const int m0   = mb << 6;

    const __bf16* qb = q  + (size_t)b * L_ * CK_;
    const __bf16* kb = kT + ((size_t)b * L_ + m0) * CK_;
    const __bf16* vb = V  + (size_t)b * C_ * L_;
    __bf16* P = &Pall[w][0];

    // K B-fragments (loop-invariant): B[k=o][col=m], real k only on quad 0
    bf16x8 kf[4];
    #pragma unroll
    for (int j = 0; j < 4; ++j) {
        bf16x8 t = {};
        if (quad == 0) t = *(const bf16x8*)(kb + (size_t)(j * 16 + l16) * CK_);
        kf[j] = t;
    }

    f32x4 acc[4][4] = {};   // [ci][j] : c-subtile x m-subtile (wave-partial)
    float csum[4] = {0.f, 0.f, 0.f, 0.f};

    for (int t = 0; t < LSPL / 256; ++t) {
        const int lbase = lq * LSPL + (t * 4 + w) * 64;   // wave-private 64 rows

        // ---- scores + exp -> P (wave-private LDS, column-major [m][l]) ----
        #pragma unroll
        for (int rg = 0; rg < 4; ++rg) {
            bf16x8 qf = {};
            if (quad == 0)
                qf = *(const bf16x8*)(qb + (size_t)(lbase + rg * 16 + l16) * CK_);
            #pragma unroll
            for (int j = 0; j < 4; ++j) {
                f32x4 s = __builtin_amdgcn_mfma_f32_16x16x32_bf16(
                    qf, kf[j], (f32x4){0.f, 0.f, 0.f, 0.f}, 0, 0, 0);
                float e0 = __expf(s[0]);
                float e1 = __expf(s[1]);
                float e2 = __expf(s[2]);
                float e3 = __expf(s[3]);
                csum[j] += (e0 + e1) + (e2 + e3);
                bf16x4 pk;
                pk[0] = (__bf16)e0; pk[1] = (__bf16)e1; pk[2] = (__bf16)e2; pk[3] = (__bf16)e3;
                // C-frag (row=quad*4+r, col=l16) -> P[m=j*16+l16][l=rg*16+quad*4+r]
                *(bf16x4*)(P + (j * 16 + l16) * S_ + rg * 16 + quad * 4) = pk;
            }
        }

        // ---- PV: D[c][m] += V[c][l] * P[l][m]  (same-wave LDS read) ----
        #pragma unroll
        for (int kk = 0; kk < 2; ++kk) {
            bf16x8 vf[4];
            #pragma unroll
            for (int ci = 0; ci < 4; ++ci)
                vf[ci] = *(const bf16x8*)(vb + (size_t)(ci * 16 + l16) * L_
                                          + lbase + kk * 32 + quad * 8);
            #pragma unroll
            for (int j = 0; j < 4; ++j) {
                bf16x8 pf = *(const bf16x8*)(P + (j * 16 + l16) * S_ + kk * 32 + quad * 8);
                #pragma unroll
                for (int ci = 0; ci < 4; ++ci)
                    acc[ci][j] = __builtin_amdgcn_mfma_f32_16x16x32_bf16(
                        vf[ci], pf, acc[ci][j], 0, 0, 0);
            }
        }
    }

    // column-sum reduction: across quads (shfl) then across waves (LDS)
    #pragma unroll
    for (int j = 0; j < 4; ++j) {
        float v = csum[j];
        v += __shfl_xor(v, 16);
        v += __shfl_xor(v, 32);
        if (lane < 16) cs[w][j * 16 + l16] = v;
    }
    __syncthreads();   // cs ready; also: all P tiles dead beyond this point
    const size_t pbase = ((size_t)b * 64 + mb) * NSPL + lq;
    if (tid < 64)
        pcs[pbase * 64 + tid] = cs[0][tid] + cs[1][tid] + cs[2][tid] + cs[3][tid];

    // ---- cross-wave accumulator reduction (fixes the R4-R6 race) ----
    // All 4 waves hold partials for the SAME (c,m) positions (different
    // l-quarters). Sum them in a 16 KB fp32 LDS tile aliased over Pall.
    float* Acc = (float*)(&Pall[0][0]);
    #pragma unroll
    for (int i = 0; i < 16; ++i) Acc[tid + i * 256] = 0.0f;
    __syncthreads();
    #pragma unroll
    for (int ci = 0; ci < 4; ++ci) {
        #pragma unroll
        for (int r = 0; r < 4; ++r) {
            const int c = ci * 16 + quad * 4 + r;
            #pragma unroll
            for (int j = 0; j < 4; ++j)
                atomicAdd(&Acc[c * 64 + j * 16 + l16], acc[ci][j][r]);
        }
    }
    __syncthreads();

    // partial acc -> bf16 [c][m], cooperative coalesced write
    __bf16* pa = pacc + pbase * (64 * 64);
    #pragma unroll
    for (int i = 0; i < 4; ++i) {
        f32x4 v = *(const f32x4*)(Acc + tid * 16 + i * 4);
        bf16x4 o;
        o[0] = (__bf16)v[0]; o[1] = (__bf16)v[1]; o[2] = (__bf16)v[2]; o[3] = (__bf16)v[3];
        *(bf16x4*)(pa + tid * 16 + i * 4) = o;
    }
}

// ---------------- Kernel 3: combine partials, normalize, residual ---------
// grid: B * 64(mb) * 4(cq); thread (ci=tid>>4, mg=tid&15) -> 1 float4 of out.
__global__ __launch_bounds__(256) void combine_kernel(
    const __bf16* __restrict__ pacc, const float* __restrict__ pcs,
    const float* __restrict__ x, const float* __restrict__ gamma_p,
    float* __restrict__ out)
{
    __shared__ float cinv[64];
    const int tid = threadIdx.x;
    const int cq  = blockIdx.x & 3;
    const int mb  = (blockIdx.x >> 2) & 63;
    const int b   = blockIdx.x >> 8;
    const size_t base = ((size_t)b * 64 + mb) * NSPL;

    if (tid < 64) {
        float s = 0.0f;
        #pragma unroll
        for (int p = 0; p < NSPL; ++p) s += pcs[(base + p) * 64 + tid];
        cinv[tid] = gamma_p[0] / s;
    }
    __syncthreads();

    const int mg = tid & 15;
    const int ci = tid >> 4;
    const int c  = cq * 16 + ci;

    float a0 = 0.f, a1 = 0.f, a2 = 0.f, a3 = 0.f;
    #pragma unroll
    for (int p = 0; p < NSPL; ++p) {
        bf16x4 v = *(const bf16x4*)(pacc + (base + p) * 4096 + c * 64 + mg * 4);
        a0 += (float)v[0]; a1 += (float)v[1]; a2 += (float)v[2]; a3 += (float)v[3];
    }
    float4 rv = *(const float4*)(cinv + mg * 4);
    const size_t idx = ((size_t)b * C_ + c) * L_ + (mb << 6) + mg * 4;
    float4 x4 = *(const float4*)(x + idx);
    float4 o;
    o.x = fmaf(rv.x, a0, x4.x);
    o.y = fmaf(rv.y, a1, x4.y);
    o.z = fmaf(rv.z, a2, x4.z);
    o.w = fmaf(rv.w, a3, x4.w);
    *(float4*)(out + idx) = o;
}

extern "C" void kernel_launch(void* const* d_in, const int* in_sizes, int n_in,
                              void* d_out, int out_size, void* d_ws, size_t ws_size,
                              hipStream_t stream) {
    const float* x  = (const float*)d_in[0];
    const float* Wq = (const float*)d_in[1];
    const float* bq = (const float*)d_in[2];
    const float* Wk = (const float*)d_in[3];
    const float* bk = (const float*)d_in[4];
    const float* Wv = (const float*)d_in[5];
    const float* bv = (const float*)d_in[6];
    const float* gm = (const float*)d_in[7];
    float* out = (float*)d_out;

    __bf16* ws   = (__bf16*)d_ws;
    __bf16* qo   = ws;                         // 262144 bf16
    __bf16* ko   = ws + 262144;                // 262144 bf16
    __bf16* vo   = ws + 524288;                // 2097152 bf16
    __bf16* pacc = ws + 2621440;               // NSPL*8*64*4096 = 4194304 bf16
    float*  pcs  = (float*)(ws + 6815744);     // NSPL*8*64*64 = 65536 f32

    qkv_kernel<<<dim3(B_ * (L_ / 64)), dim3(256), 0, stream>>>(
        x, Wq, bq, Wk, bk, Wv, bv, qo, ko, vo);
    attn_kernel<<<dim3(B_ * 64 * NSPL), dim3(256), 0, stream>>>(
        qo, ko, vo, pacc, pcs);
    combine_kernel<<<dim3(B_ * 64 * 4), dim3(256), 0, stream>>>(
        pacc, pcs, x, gm, out);
}

// Round 8
// 233.389 us; speedup vs baseline: 1.0364x; 1.0364x over previous
//
#include <hip/hip_runtime.h>
#include <math.h>

#define B_   8
#define C_   64
#define CK_  8
#define L_   4096
#define NSPL 2
#define LSPL (L_ / NSPL)

typedef __attribute__((ext_vector_type(8))) __bf16 bf16x8;
typedef __attribute__((ext_vector_type(4))) __bf16 bf16x4;
typedef __attribute__((ext_vector_type(4))) float  f32x4;
typedef __attribute__((ext_vector_type(4))) short  s16x4;

static __device__ __forceinline__ s16x4 bc(bf16x4 v) {
    return __builtin_bit_cast(s16x4, v);
}

// ---------------- Kernel 1: QKV projection -> bf16 (unchanged from R7) ----
// x: [B,C,L] fp32 -> q: [B,L,8] ; kT: [B,L,8] ; vo: [B,C,L]
__global__ __launch_bounds__(256) void qkv_kernel(
    const float* __restrict__ x,
    const float* __restrict__ Wq, const float* __restrict__ bq,
    const float* __restrict__ Wk, const float* __restrict__ bk,
    const float* __restrict__ Wv, const float* __restrict__ bv,
    __bf16* __restrict__ qo, __bf16* __restrict__ ko, __bf16* __restrict__ vo)
{
    __shared__ float LWq[CK_ * C_];
    __shared__ float LWk[CK_ * C_];
    __shared__ float LWv[C_ * C_];      // row-major [c_out][c_in]
    __shared__ __bf16 Lqs[64 * 8];
    __shared__ __bf16 Lks[64 * 8];

    const int tid = threadIdx.x;
    if (tid < 128) {
        ((float4*)LWq)[tid] = ((const float4*)Wq)[tid];
        ((float4*)LWk)[tid] = ((const float4*)Wk)[tid];
    }
    #pragma unroll
    for (int j = 0; j < 4; ++j)
        ((float4*)LWv)[tid + j * 256] = ((const float4*)Wv)[tid + j * 256];
    __syncthreads();

    const int b  = blockIdx.x >> 6;
    const int l0 = (blockIdx.x & 63) << 6;
    const int lg = tid & 15;
    const int g  = tid >> 4;

    float va[4][4];
    float qk[4];
    #pragma unroll
    for (int j = 0; j < 4; ++j) {
        float bb = bv[4 * g + j];
        va[j][0] = bb; va[j][1] = bb; va[j][2] = bb; va[j][3] = bb;
    }
    {
        float bb = (g < 8) ? bq[g] : bk[g - 8];
        qk[0] = bb; qk[1] = bb; qk[2] = bb; qk[3] = bb;
    }
    const float* wqk = (g < 8) ? (LWq + g * C_) : (LWk + (g - 8) * C_);

    const float* xp = x + ((size_t)b * C_) * L_ + l0 + lg * 4;
    #pragma unroll 4
    for (int c4 = 0; c4 < 16; ++c4) {
        float4 xv[4];
        #pragma unroll
        for (int u = 0; u < 4; ++u)
            xv[u] = *(const float4*)(xp + (size_t)(4 * c4 + u) * L_);
        #pragma unroll
        for (int j = 0; j < 4; ++j) {
            float4 wv = ((const float4*)(LWv + (4 * g + j) * C_))[c4];
            float* a = va[j];
            a[0]=fmaf(wv.x,xv[0].x,a[0]); a[1]=fmaf(wv.x,xv[0].y,a[1]); a[2]=fmaf(wv.x,xv[0].z,a[2]); a[3]=fmaf(wv.x,xv[0].w,a[3]);
            a[0]=fmaf(wv.y,xv[1].x,a[0]); a[1]=fmaf(wv.y,xv[1].y,a[1]); a[2]=fmaf(wv.y,xv[1].z,a[2]); a[3]=fmaf(wv.y,xv[1].w,a[3]);
            a[0]=fmaf(wv.z,xv[2].x,a[0]); a[1]=fmaf(wv.z,xv[2].y,a[1]); a[2]=fmaf(wv.z,xv[2].z,a[2]); a[3]=fmaf(wv.z,xv[2].w,a[3]);
            a[0]=fmaf(wv.w,xv[3].x,a[0]); a[1]=fmaf(wv.w,xv[3].y,a[1]); a[2]=fmaf(wv.w,xv[3].z,a[2]); a[3]=fmaf(wv.w,xv[3].w,a[3]);
        }
        {
            float4 wv = ((const float4*)wqk)[c4];
            qk[0]=fmaf(wv.x,xv[0].x,qk[0]); qk[1]=fmaf(wv.x,xv[0].y,qk[1]); qk[2]=fmaf(wv.x,xv[0].z,qk[2]); qk[3]=fmaf(wv.x,xv[0].w,qk[3]);
            qk[0]=fmaf(wv.y,xv[1].x,qk[0]); qk[1]=fmaf(wv.y,xv[1].y,qk[1]); qk[2]=fmaf(wv.y,xv[1].z,qk[2]); qk[3]=fmaf(wv.y,xv[1].w,qk[3]);
            qk[0]=fmaf(wv.z,xv[2].x,qk[0]); qk[1]=fmaf(wv.z,xv[2].y,qk[1]); qk[2]=fmaf(wv.z,xv[2].z,qk[2]); qk[3]=fmaf(wv.z,xv[2].w,qk[3]);
            qk[0]=fmaf(wv.w,xv[3].x,qk[0]); qk[1]=fmaf(wv.w,xv[3].y,qk[1]); qk[2]=fmaf(wv.w,xv[3].z,qk[2]); qk[3]=fmaf(wv.w,xv[3].w,qk[3]);
        }
    }

    #pragma unroll
    for (int j = 0; j < 4; ++j) {
        bf16x4 vv;
        vv[0]=(__bf16)va[j][0]; vv[1]=(__bf16)va[j][1]; vv[2]=(__bf16)va[j][2]; vv[3]=(__bf16)va[j][3];
        *(bf16x4*)(vo + ((size_t)b * C_ + 4 * g + j) * L_ + l0 + lg * 4) = vv;
    }
    #pragma unroll
    for (int u = 0; u < 4; ++u) {
        if (g < 8) Lqs[(lg * 4 + u) * 8 + g]       = (__bf16)qk[u];
        else       Lks[(lg * 4 + u) * 8 + (g - 8)] = (__bf16)qk[u];
    }
    __syncthreads();
    if (tid < 64) {
        *(bf16x8*)(qo + ((size_t)b * L_ + l0 + tid) * 8) = *(bf16x8*)(Lqs + tid * 8);
        *(bf16x8*)(ko + ((size_t)b * L_ + l0 + tid) * 8) = *(bf16x8*)(Lks + tid * 8);
    }
}

// ---------------- Kernel 2: attention phase-1, direct-feed, no spill ------
// 16x16x16bf16_1k: score C-fragment layout == PV B-operand layout -> the
// exp'd probabilities feed the PV MFMA directly in registers. No LDS in the
// K-loop, no barriers. Cross-wave accumulator reduction in the epilogue
// (R7's race fix). __launch_bounds__(256,3): ~105 live VGPRs, cap 170.
// grid: B * 64(mb) * NSPL.
__global__ __launch_bounds__(256, 3) void attn_kernel(
    const __bf16* __restrict__ q, const __bf16* __restrict__ kT,
    const __bf16* __restrict__ V,
    __bf16* __restrict__ pacc, float* __restrict__ pcs)
{
    __shared__ float cs[4][64];
    __shared__ float Acc[64 * 64];   // 16 KB cross-wave reduction tile

    const int tid  = threadIdx.x;
    const int w    = tid >> 6;
    const int lane = tid & 63;
    const int quad = lane >> 4;
    const int l16  = lane & 15;
    const int lq   = blockIdx.x & (NSPL - 1);
    const int mb   = (blockIdx.x / NSPL) & 63;
    const int b    = blockIdx.x / (NSPL * 64);
    const int m0   = mb << 6;

    const __bf16* qb = q  + (size_t)b * L_ * CK_;
    const __bf16* kb = kT + ((size_t)b * L_ + m0) * CK_;
    const __bf16* vb = V  + (size_t)b * C_ * L_;

    // K B-fragments (loop-invariant): B[k=quad*4+i][col=j*16+l16], quads 2,3 zero
    s16x4 kf[4];
    #pragma unroll
    for (int j = 0; j < 4; ++j) {
        bf16x4 t = {};
        if (quad < 2) t = *(const bf16x4*)(kb + (size_t)(j * 16 + l16) * CK_ + quad * 4);
        kf[j] = bc(t);
    }

    f32x4 acc[4][4] = {};   // [ci][j] c-subtile x m-subtile (wave-partial over l)
    float csum[4] = {0.f, 0.f, 0.f, 0.f};

    for (int t = 0; t < LSPL / 64; ++t) {
        const int lb = lq * LSPL + t * 64 + w * 16;   // wave's 16 l-rows this iter

        // V A-fragments: lane holds V[c=ci*16+l16][l=lb+quad*4+i]
        s16x4 vf[4];
        #pragma unroll
        for (int ci = 0; ci < 4; ++ci)
            vf[ci] = bc(*(const bf16x4*)(vb + (size_t)(ci * 16 + l16) * L_ + lb + quad * 4));
        // Q A-fragment: A[row=l16][k=o=quad*4+i], quads 2,3 zero (K=8 real)
        bf16x4 tq = {};
        if (quad < 2) tq = *(const bf16x4*)(qb + (size_t)(lb + l16) * CK_ + quad * 4);
        s16x4 qf = bc(tq);

        #pragma unroll
        for (int j = 0; j < 4; ++j) {
            f32x4 s = __builtin_amdgcn_mfma_f32_16x16x16bf16_1k(
                qf, kf[j], (f32x4){0.f, 0.f, 0.f, 0.f}, 0, 0, 0);
            float e0 = __expf(s[0]);
            float e1 = __expf(s[1]);
            float e2 = __expf(s[2]);
            float e3 = __expf(s[3]);
            csum[j] += (e0 + e1) + (e2 + e3);
            bf16x4 pk;
            pk[0] = (__bf16)e0; pk[1] = (__bf16)e1; pk[2] = (__bf16)e2; pk[3] = (__bf16)e3;
            s16x4 pf = bc(pk);   // C-layout == B-layout: direct register feed
            #pragma unroll
            for (int ci = 0; ci < 4; ++ci)
                acc[ci][j] = __builtin_amdgcn_mfma_f32_16x16x16bf16_1k(
                    vf[ci], pf, acc[ci][j], 0, 0, 0);
        }
    }

    // column-sums: reduce over quads (shfl) then stage per-wave in LDS
    #pragma unroll
    for (int j = 0; j < 4; ++j) {
        float v = csum[j];
        v += __shfl_xor(v, 16);
        v += __shfl_xor(v, 32);
        if (lane < 16) cs[w][j * 16 + l16] = v;
    }
    // zero the reduction tile, then one barrier covers cs + Acc readiness
    #pragma unroll
    for (int i = 0; i < 16; ++i) Acc[tid + i * 256] = 0.0f;
    __syncthreads();

    const size_t pbase = ((size_t)b * 64 + mb) * NSPL + lq;
    if (tid < 64)
        pcs[pbase * 64 + tid] = cs[0][tid] + cs[1][tid] + cs[2][tid] + cs[3][tid];

    // cross-wave accumulator reduction (all 4 waves hold the same (c,m) grid)
    #pragma unroll
    for (int ci = 0; ci < 4; ++ci) {
        #pragma unroll
        for (int r = 0; r < 4; ++r) {
            const int c = ci * 16 + quad * 4 + r;
            #pragma unroll
            for (int j = 0; j < 4; ++j)
                atomicAdd(&Acc[c * 64 + j * 16 + l16], acc[ci][j][r]);
        }
    }
    __syncthreads();

    // partial acc -> bf16 [c][m], cooperative coalesced write
    __bf16* pa = pacc + pbase * (64 * 64);
    #pragma unroll
    for (int i = 0; i < 4; ++i) {
        f32x4 v = *(const f32x4*)(Acc + tid * 16 + i * 4);
        bf16x4 o;
        o[0] = (__bf16)v[0]; o[1] = (__bf16)v[1]; o[2] = (__bf16)v[2]; o[3] = (__bf16)v[3];
        *(bf16x4*)(pa + tid * 16 + i * 4) = o;
    }
}

// ---------------- Kernel 3: combine partials, normalize, residual ---------
// grid: B * 64(mb) * 4(cq); thread (ci=tid>>4, mg=tid&15) -> 1 float4 of out.
__global__ __launch_bounds__(256) void combine_kernel(
    const __bf16* __restrict__ pacc, const float* __restrict__ pcs,
    const float* __restrict__ x, const float* __restrict__ gamma_p,
    float* __restrict__ out)
{
    __shared__ float cinv[64];
    const int tid = threadIdx.x;
    const int cq  = blockIdx.x & 3;
    const int mb  = (blockIdx.x >> 2) & 63;
    const int b   = blockIdx.x >> 8;
    const size_t base = ((size_t)b * 64 + mb) * NSPL;

    if (tid < 64) {
        float s = 0.0f;
        #pragma unroll
        for (int p = 0; p < NSPL; ++p) s += pcs[(base + p) * 64 + tid];
        cinv[tid] = gamma_p[0] / s;
    }
    __syncthreads();

    const int mg = tid & 15;
    const int ci = tid >> 4;
    const int c  = cq * 16 + ci;

    float a0 = 0.f, a1 = 0.f, a2 = 0.f, a3 = 0.f;
    #pragma unroll
    for (int p = 0; p < NSPL; ++p) {
        bf16x4 v = *(const bf16x4*)(pacc + (base + p) * 4096 + c * 64 + mg * 4);
        a0 += (float)v[0]; a1 += (float)v[1]; a2 += (float)v[2]; a3 += (float)v[3];
    }
    float4 rv = *(const float4*)(cinv + mg * 4);
    const size_t idx = ((size_t)b * C_ + c) * L_ + (mb << 6) + mg * 4;
    float4 x4 = *(const float4*)(x + idx);
    float4 o;
    o.x = fmaf(rv.x, a0, x4.x);
    o.y = fmaf(rv.y, a1, x4.y);
    o.z = fmaf(rv.z, a2, x4.z);
    o.w = fmaf(rv.w, a3, x4.w);
    *(float4*)(out + idx) = o;
}

extern "C" void kernel_launch(void* const* d_in, const int* in_sizes, int n_in,
                              void* d_out, int out_size, void* d_ws, size_t ws_size,
                              hipStream_t stream) {
    const float* x  = (const float*)d_in[0];
    const float* Wq = (const float*)d_in[1];
    const float* bq = (const float*)d_in[2];
    const float* Wk = (const float*)d_in[3];
    const float* bk = (const float*)d_in[4];
    const float* Wv = (const float*)d_in[5];
    const float* bv = (const float*)d_in[6];
    const float* gm = (const float*)d_in[7];
    float* out = (float*)d_out;

    __bf16* ws   = (__bf16*)d_ws;
    __bf16* qo   = ws;                         // 262144 bf16
    __bf16* ko   = ws + 262144;                // 262144 bf16
    __bf16* vo   = ws + 524288;                // 2097152 bf16
    __bf16* pacc = ws + 2621440;               // NSPL*8*64*4096 = 4194304 bf16
    float*  pcs  = (float*)(ws + 6815744);     // NSPL*8*64*64 = 65536 f32

    qkv_kernel<<<dim3(B_ * (L_ / 64)), dim3(256), 0, stream>>>(
        x, Wq, bq, Wk, bk, Wv, bv, qo, ko, vo);
    attn_kernel<<<dim3(B_ * 64 * NSPL), dim3(256), 0, stream>>>(
        qo, ko, vo, pacc, pcs);
    combine_kernel<<<dim3(B_ * 64 * 4), dim3(256), 0, stream>>>(
        pacc, pcs, x, gm, out);
}